// Round 3
// baseline (97.794 us; speedup 1.0000x reference)
//
#include <hip/hip_runtime.h>
#include <math.h>

#define DT_STEP (1.0f / 120.0f)
#define G_ACC 9.81f
#define KS 100.0f

// One independent 2x2 Kalman filter with scalar measurement of state 0.
// FT=0: (pos_x, vel_x), FT=1: (pos_y, vel_y)  -- nonlinear friction on vel
// FT=2: (theta, omega)                        -- linear, angle-wrapped innovation
// z values come from LDS at stride 3 (zp[3*t]).
template <int FT>
__device__ __forceinline__ float run_filter(
    const float fric, const float damp,
    const float R, const float Qp, const float Qv,
    float s0, float s1,
    const float* __restrict__ zp, int T)
{
    const float fG = fric * G_ACC;
    const float a55 = 1.0f - DT_STEP * damp;
    const float PI15 = 4.7123889803846899f;
    const float TWOPI = 6.2831853071795865f;

    float a = 0.01f, b = 0.0f, c = 0.01f;   // P = [[a,b],[b,c]]
    float loss = 0.0f;

    float z = zp[0];  // current measurement, prefetched

    for (int t = 0; t < T; t++) {
        // prefetch next step's z from LDS while this step computes
        int tn = t + 1; if (tn > T - 1) tn = T - 1;
        const float zn = zp[3 * tn];

        // ---- predict ----
        float s0p, s1p, dv;
        if constexpr (FT < 2) {
            // tanh(KS*s1) = 1 - 2/(exp(2*KS*s1)+1)  (saturates cleanly to +-1)
            const float e = __expf(2.0f * KS * s1);
            const float th = 1.0f - 2.0f / (e + 1.0f);
            s0p = s0 + DT_STEP * s1;
            s1p = s1 - DT_STEP * (damp * s1 + fG * th);
            dv = 1.0f - DT_STEP * (damp + fG * KS * (1.0f - th * th));
        } else {
            s0p = s0 + DT_STEP * s1;
            s1p = a55 * s1;
            dv = a55;
        }

        // ---- P_pred = F P F^T + Q, F = [[1, DT],[0, dv]] ----
        const float M00 = a + DT_STEP * b;
        const float M01 = b + DT_STEP * c;
        const float Pp00 = M00 + DT_STEP * M01 + Qp;
        const float Pp01 = dv * M01;
        const float Pp11 = dv * dv * c + Qv;

        // ---- innovation ----
        float y = z - s0p;
        if constexpr (FT == 2) {
            if (y > PI15) y -= TWOPI;
            else if (y < -PI15) y += TWOPI;
        }

        // ---- scalar-measurement update ----
        const float S = Pp00 + R;
        const float Si = 1.0f / S;
        const float K0 = Pp00 * Si;
        const float K1 = Pp01 * Si;

        s0 = s0p + K0 * y;
        s1 = s1p + K1 * y;

        const float omk = 1.0f - K0;
        a = Pp00 * omk;
        b = Pp01 * omk;
        c = Pp11 - K1 * Pp01;

        loss += __logf(S) + y * y * Si;
        z = zn;
    }
    return loss;
}

// Block = 192 threads (3 waves). Wave w runs filter type w for 64 segments.
// Measurements for the block's 64 segments staged into LDS with coalesced
// global reads; row stride padded to 3T+1 so compute reads are 2-way (free).
__global__ __launch_bounds__(192) void ekf_split_lds(
    const float* __restrict__ params,
    const float* __restrict__ cp,
    const float* __restrict__ init_state,
    const float* __restrict__ meas,
    float* __restrict__ out,
    int N, int T)
{
    extern __shared__ float zlds[];
    const int tid = threadIdx.x;
    const int wave = tid >> 6;   // filter type 0/1/2 (wave-uniform)
    const int lane = tid & 63;   // segment within block
    const int segBase = blockIdx.x * 64;
    const int row = 3 * T;       // floats per segment
    const int stride = row + 1;  // padded LDS row stride

    // ---- stage: 64 segments, coalesced 768B global reads, conflict-free LDS writes ----
    const float* gsrc = meas + (size_t)segBase * row;
    for (int s = 0; s < 64; s++) {
        for (int j = tid; j < row; j += 192)
            zlds[s * stride + j] = gsrc[(size_t)s * row + j];
    }
    __syncthreads();

    // ---- per-thread filter ----
    const float fric = fabsf(params[0]);
    const float damp = fabsf(params[1]);

    const float R  = __expf(cp[wave]);
    const float Qp = __expf((wave == 2) ? cp[5] : cp[3]);
    const float Qv = __expf((wave == 2) ? cp[6] : cp[4]);

    const int seg = segBase + lane;
    const float* sb = init_state + (size_t)seg * 6;
    const int s0i = (wave == 2) ? 4 : wave;
    const int s1i = (wave == 2) ? 5 : wave + 2;
    const float s0 = sb[s0i];
    const float s1 = sb[s1i];

    const float* zp = zlds + lane * stride + wave;

    float local;
    if (wave == 0)      local = run_filter<0>(fric, damp, R, Qp, Qv, s0, s1, zp, T);
    else if (wave == 1) local = run_filter<1>(fric, damp, R, Qp, Qv, s0, s1, zp, T);
    else                local = run_filter<2>(fric, damp, R, Qp, Qv, s0, s1, zp, T);

    // ---- wave-level reduction, one atomic per wave ----
#pragma unroll
    for (int off = 32; off > 0; off >>= 1)
        local += __shfl_down(local, off, 64);

    if (lane == 0) {
        atomicAdd(out, local * 0.5f / (float)N);
    }
}

extern "C" void kernel_launch(void* const* d_in, const int* in_sizes, int n_in,
                              void* d_out, int out_size, void* d_ws, size_t ws_size,
                              hipStream_t stream) {
    const float* params     = (const float*)d_in[0];
    const float* cov_params = (const float*)d_in[1];
    const float* init_state = (const float*)d_in[2];
    const float* meas       = (const float*)d_in[3];
    float* out = (float*)d_out;

    const int N = in_sizes[2] / 6;
    const int T = in_sizes[3] / (N * 3);

    hipMemsetAsync(out, 0, sizeof(float), stream);

    const int grid = N / 64;                        // N=8192 -> 128 blocks
    const size_t shmem = (size_t)64 * (3 * T + 1) * sizeof(float);  // 49408 B @ T=64
    ekf_split_lds<<<grid, 192, shmem, stream>>>(params, cov_params, init_state, meas, out, N, T);
}

// Round 4
// 88.385 us; speedup vs baseline: 1.1065x; 1.1065x over previous
//
#include <hip/hip_runtime.h>
#include <math.h>

#define DT_STEP (1.0f / 120.0f)
#define G_ACC 9.81f
#define KS 100.0f

// ---------------------------------------------------------------------------
// Kernel 1: transpose meas (N, T, 3) -> ws[j][n], j = t*3 + c.
// Block = 256 threads handles 64 segments. float4 global reads (independent,
// pipelined), LDS tile with +1 padded stride, coalesced 256B global writes.
// ---------------------------------------------------------------------------
__global__ __launch_bounds__(256) void transpose_kernel(
    const float* __restrict__ meas, float* __restrict__ ws, int N, int row /*3T*/)
{
    extern __shared__ float tile[];       // 64 x (row+1)
    const int tid = threadIdx.x;
    const int segBase = blockIdx.x * 64;
    const int stride = row + 1;
    const int nf4 = 64 * row / 4;         // float4 elements in this block's chunk

    const float4* src = (const float4*)(meas + (size_t)segBase * row);
#pragma unroll 4
    for (int f4 = tid; f4 < nf4; f4 += 256) {
        float4 v = src[f4];
        int f = f4 * 4;
        int s = f / row;
        int j = f - s * row;
        float* dst = tile + s * stride + j;
        dst[0] = v.x; dst[1] = v.y; dst[2] = v.z; dst[3] = v.w;
    }
    __syncthreads();

    const int n = tid & 63;               // segment within block
    const int jb = tid >> 6;              // 0..3
    for (int j = jb; j < row; j += 4) {   // LDS read (n+j)%32 -> 2-way, free
        ws[(size_t)j * N + segBase + n] = tile[n * stride + j];
    }
}

// ---------------------------------------------------------------------------
// EKF math: one 2x2 filter per thread, scalar measurement of state 0.
// FT=0/1: (pos,vel) with tanh friction; FT=2: (theta,omega), angle wrap.
// ---------------------------------------------------------------------------
template <int FT>
__device__ __forceinline__ void ekf_step(
    const float fric, const float damp, const float fG, const float a55,
    const float R, const float Qp, const float Qv,
    float& s0, float& s1, float& a, float& b, float& c,
    const float z, float& loss)
{
    const float PI15 = 4.7123889803846899f;
    const float TWOPI = 6.2831853071795865f;

    float s0p, s1p, dv;
    if constexpr (FT < 2) {
        const float e = __expf(2.0f * KS * s1);
        const float th = 1.0f - 2.0f / (e + 1.0f);
        s0p = s0 + DT_STEP * s1;
        s1p = s1 - DT_STEP * (damp * s1 + fG * th);
        dv = 1.0f - DT_STEP * (damp + fG * KS * (1.0f - th * th));
    } else {
        s0p = s0 + DT_STEP * s1;
        s1p = a55 * s1;
        dv = a55;
    }

    const float M00 = a + DT_STEP * b;
    const float M01 = b + DT_STEP * c;
    const float Pp00 = M00 + DT_STEP * M01 + Qp;
    const float Pp01 = dv * M01;
    const float Pp11 = dv * dv * c + Qv;

    float y = z - s0p;
    if constexpr (FT == 2) {
        if (y > PI15) y -= TWOPI;
        else if (y < -PI15) y += TWOPI;
    }

    const float S = Pp00 + R;
    const float Si = 1.0f / S;
    const float K0 = Pp00 * Si;
    const float K1 = Pp01 * Si;

    s0 = s0p + K0 * y;
    s1 = s1p + K1 * y;

    const float omk = 1.0f - K0;
    a = Pp00 * omk;
    b = Pp01 * omk;
    c = Pp11 - K1 * Pp01;

    loss += __logf(S) + y * y * Si;
}

template <int TT, int FT>
__device__ __forceinline__ float run_filter_T(
    const float fric, const float damp, const float R, const float Qp, const float Qv,
    float s0, float s1, const float (&z)[TT])
{
    const float fG = fric * G_ACC;
    const float a55 = 1.0f - DT_STEP * damp;
    float a = 0.01f, b = 0.0f, c = 0.01f;
    float loss = 0.0f;
#pragma unroll
    for (int t = 0; t < TT; t++)
        ekf_step<FT>(fric, damp, fG, a55, R, Qp, Qv, s0, s1, a, b, c, z[t], loss);
    return loss;
}

// ---------------------------------------------------------------------------
// Kernel 2 (T known at compile time): preload ALL T measurements into
// registers (coalesced dword loads, all in flight), then pure-register chain.
// ---------------------------------------------------------------------------
template <int TT>
__global__ __launch_bounds__(64) void ekf_compute_T(
    const float* __restrict__ params, const float* __restrict__ cp,
    const float* __restrict__ init_state, const float* __restrict__ ws,
    float* __restrict__ out, int N)
{
    const int lane = threadIdx.x & 63;
    const int seg = blockIdx.x * 64 + lane;
    const int ft = blockIdx.y;
    float local = 0.0f;

    if (seg < N) {
        float z[TT];
        const float* zp = ws + (size_t)ft * N + seg;
#pragma unroll
        for (int t = 0; t < TT; t++) z[t] = zp[(size_t)(3 * t) * N];

        const float fric = fabsf(params[0]);
        const float damp = fabsf(params[1]);
        const float R  = __expf(cp[ft]);
        const float Qp = __expf((ft == 2) ? cp[5] : cp[3]);
        const float Qv = __expf((ft == 2) ? cp[6] : cp[4]);

        const float* sb = init_state + (size_t)seg * 6;
        const float s0 = sb[(ft == 2) ? 4 : ft];
        const float s1 = sb[(ft == 2) ? 5 : ft + 2];

        if (ft == 0)      local = run_filter_T<TT, 0>(fric, damp, R, Qp, Qv, s0, s1, z);
        else if (ft == 1) local = run_filter_T<TT, 1>(fric, damp, R, Qp, Qv, s0, s1, z);
        else              local = run_filter_T<TT, 2>(fric, damp, R, Qp, Qv, s0, s1, z);
    }

#pragma unroll
    for (int off = 32; off > 0; off >>= 1)
        local += __shfl_down(local, off, 64);
    if (lane == 0) atomicAdd(out, local * 0.5f / (float)N);
}

// Generic fallback for runtime T (same structure, 2-ahead prefetch).
__global__ __launch_bounds__(64) void ekf_compute_gen(
    const float* __restrict__ params, const float* __restrict__ cp,
    const float* __restrict__ init_state, const float* __restrict__ ws,
    float* __restrict__ out, int N, int T)
{
    const int lane = threadIdx.x & 63;
    const int seg = blockIdx.x * 64 + lane;
    const int ft = blockIdx.y;
    float local = 0.0f;

    if (seg < N) {
        const float fric = fabsf(params[0]);
        const float damp = fabsf(params[1]);
        const float R  = __expf(cp[ft]);
        const float Qp = __expf((ft == 2) ? cp[5] : cp[3]);
        const float Qv = __expf((ft == 2) ? cp[6] : cp[4]);
        const float* sb = init_state + (size_t)seg * 6;
        float s0 = sb[(ft == 2) ? 4 : ft];
        float s1 = sb[(ft == 2) ? 5 : ft + 2];
        const float fG = fric * G_ACC;
        const float a55 = 1.0f - DT_STEP * damp;
        float a = 0.01f, b = 0.0f, c = 0.01f;

        const float* zp = ws + (size_t)ft * N + seg;
        float zc = zp[0];
        float zn = (T > 1) ? zp[(size_t)3 * N] : zc;
        for (int t = 0; t < T; t++) {
            int tn = t + 2; if (tn > T - 1) tn = T - 1;
            const float z2 = zp[(size_t)(3 * tn) * N];
            if (ft == 0)      ekf_step<0>(fric, damp, fG, a55, R, Qp, Qv, s0, s1, a, b, c, zc, local);
            else if (ft == 1) ekf_step<1>(fric, damp, fG, a55, R, Qp, Qv, s0, s1, a, b, c, zc, local);
            else              ekf_step<2>(fric, damp, fG, a55, R, Qp, Qv, s0, s1, a, b, c, zc, local);
            zc = zn; zn = z2;
        }
    }

#pragma unroll
    for (int off = 32; off > 0; off >>= 1)
        local += __shfl_down(local, off, 64);
    if (lane == 0) atomicAdd(out, local * 0.5f / (float)N);
}

extern "C" void kernel_launch(void* const* d_in, const int* in_sizes, int n_in,
                              void* d_out, int out_size, void* d_ws, size_t ws_size,
                              hipStream_t stream) {
    const float* params     = (const float*)d_in[0];
    const float* cov_params = (const float*)d_in[1];
    const float* init_state = (const float*)d_in[2];
    const float* meas       = (const float*)d_in[3];
    float* out = (float*)d_out;
    float* ws  = (float*)d_ws;

    const int N = in_sizes[2] / 6;
    const int T = in_sizes[3] / (N * 3);
    const int row = 3 * T;

    hipMemsetAsync(out, 0, sizeof(float), stream);

    const int nblk = (N + 63) / 64;
    const size_t shmem = (size_t)64 * (row + 1) * sizeof(float);
    transpose_kernel<<<nblk, 256, shmem, stream>>>(meas, ws, N, row);

    dim3 grid(nblk, 3);
    if (T == 64) {
        ekf_compute_T<64><<<grid, 64, 0, stream>>>(params, cov_params, init_state, ws, out, N);
    } else {
        ekf_compute_gen<<<grid, 64, 0, stream>>>(params, cov_params, init_state, ws, out, N, T);
    }
}

// Round 5
// 81.589 us; speedup vs baseline: 1.1986x; 1.0833x over previous
//
#include <hip/hip_runtime.h>
#include <math.h>

#define DT_STEP (1.0f / 120.0f)
#define G_ACC 9.81f
#define KS 100.0f

// ---------------------------------------------------------------------------
// One independent 2x2 Kalman filter per thread, scalar measurement of state 0.
// FT=0: (pos_x, vel_x), FT=1: (pos_y, vel_y)  -- nonlinear tanh friction
// FT=2: (theta, omega)                        -- linear, angle-wrapped innov.
// All T measurements preloaded into registers (64 independent gathers, one
// latency round-trip), then a pure-register dependence chain.
// ---------------------------------------------------------------------------
template <int FT>
__device__ __forceinline__ void ekf_step(
    const float damp, const float fG, const float a55,
    const float R, const float Qp, const float Qv,
    float& s0, float& s1, float& a, float& b, float& c,
    const float z, float& loss)
{
    const float PI15 = 4.7123889803846899f;
    const float TWOPI = 6.2831853071795865f;

    float s0p, s1p, dv;
    if constexpr (FT < 2) {
        // tanh(KS*s1) = 1 - 2/(exp(2*KS*s1)+1), saturates cleanly to +-1
        const float e = __expf(2.0f * KS * s1);
        const float th = 1.0f - 2.0f / (e + 1.0f);
        s0p = s0 + DT_STEP * s1;
        s1p = s1 - DT_STEP * (damp * s1 + fG * th);
        dv = 1.0f - DT_STEP * (damp + fG * KS * (1.0f - th * th));
    } else {
        s0p = s0 + DT_STEP * s1;
        s1p = a55 * s1;
        dv = a55;
    }

    // P_pred = F P F^T + Q, F = [[1, DT],[0, dv]], P = [[a,b],[b,c]]
    const float M00 = a + DT_STEP * b;
    const float M01 = b + DT_STEP * c;
    const float Pp00 = M00 + DT_STEP * M01 + Qp;
    const float Pp01 = dv * M01;
    const float Pp11 = dv * dv * c + Qv;

    float y = z - s0p;
    if constexpr (FT == 2) {
        if (y > PI15) y -= TWOPI;
        else if (y < -PI15) y += TWOPI;
    }

    const float S = Pp00 + R;
    const float Si = 1.0f / S;
    const float K0 = Pp00 * Si;
    const float K1 = Pp01 * Si;

    s0 = s0p + K0 * y;
    s1 = s1p + K1 * y;

    const float omk = 1.0f - K0;
    a = Pp00 * omk;
    b = Pp01 * omk;
    c = Pp11 - K1 * Pp01;

    loss += __logf(S) + y * y * Si;
}

template <int TT, int FT>
__device__ __forceinline__ float run_filter(
    const float damp, const float fG, const float a55,
    const float R, const float Qp, const float Qv,
    float s0, float s1, const float (&z)[TT])
{
    float a = 0.01f, b = 0.0f, c = 0.01f;
    float loss = 0.0f;
#pragma unroll
    for (int t = 0; t < TT; t++)
        ekf_step<FT>(damp, fG, a55, R, Qp, Qv, s0, s1, a, b, c, z[t], loss);
    return loss;
}

template <int TT>
__global__ __launch_bounds__(64) void ekf_reg_kernel(
    const float* __restrict__ params, const float* __restrict__ cp,
    const float* __restrict__ init_state, const float* __restrict__ meas,
    float* __restrict__ out, int N)
{
    const int lane = threadIdx.x & 63;
    const int seg = blockIdx.x * 64 + lane;
    const int ft = blockIdx.y;   // wave-uniform filter type
    float local = 0.0f;

    if (seg < N) {
        // ---- preload all T measurement values (independent loads, in flight) ----
        const float* zrow = meas + (size_t)seg * (3 * TT) + ft;
        float z[TT];
#pragma unroll
        for (int t = 0; t < TT; t++) z[t] = zrow[3 * t];

        const float fric = fabsf(params[0]);
        const float damp = fabsf(params[1]);
        const float fG = fric * G_ACC;
        const float a55 = 1.0f - DT_STEP * damp;

        const float R  = __expf(cp[ft]);
        const float Qp = __expf((ft == 2) ? cp[5] : cp[3]);
        const float Qv = __expf((ft == 2) ? cp[6] : cp[4]);

        const float* sb = init_state + (size_t)seg * 6;
        const float s0 = sb[(ft == 2) ? 4 : ft];
        const float s1 = sb[(ft == 2) ? 5 : ft + 2];

        if (ft == 0)      local = run_filter<TT, 0>(damp, fG, a55, R, Qp, Qv, s0, s1, z);
        else if (ft == 1) local = run_filter<TT, 1>(damp, fG, a55, R, Qp, Qv, s0, s1, z);
        else              local = run_filter<TT, 2>(damp, fG, a55, R, Qp, Qv, s0, s1, z);
    }

    // wave-level reduction, one atomic per block (block = 1 wave)
#pragma unroll
    for (int off = 32; off > 0; off >>= 1)
        local += __shfl_down(local, off, 64);

    if (lane == 0) atomicAdd(out, local * 0.5f / (float)N);
}

// Generic-T fallback: same structure with rolling 4-deep prefetch.
__global__ __launch_bounds__(64) void ekf_gen_kernel(
    const float* __restrict__ params, const float* __restrict__ cp,
    const float* __restrict__ init_state, const float* __restrict__ meas,
    float* __restrict__ out, int N, int T)
{
    const int lane = threadIdx.x & 63;
    const int seg = blockIdx.x * 64 + lane;
    const int ft = blockIdx.y;
    float local = 0.0f;

    if (seg < N) {
        const float fric = fabsf(params[0]);
        const float damp = fabsf(params[1]);
        const float fG = fric * G_ACC;
        const float a55 = 1.0f - DT_STEP * damp;
        const float R  = __expf(cp[ft]);
        const float Qp = __expf((ft == 2) ? cp[5] : cp[3]);
        const float Qv = __expf((ft == 2) ? cp[6] : cp[4]);
        const float* sb = init_state + (size_t)seg * 6;
        float s0 = sb[(ft == 2) ? 4 : ft];
        float s1 = sb[(ft == 2) ? 5 : ft + 2];
        float a = 0.01f, b = 0.0f, c = 0.01f;

        const float* zrow = meas + (size_t)seg * (3 * T) + ft;
        float zbuf[4];
#pragma unroll
        for (int k = 0; k < 4; k++) zbuf[k] = zrow[3 * min(k, T - 1)];
        for (int t = 0; t < T; t++) {
            const float z = zbuf[0];
            zbuf[0] = zbuf[1]; zbuf[1] = zbuf[2]; zbuf[2] = zbuf[3];
            zbuf[3] = zrow[3 * min(t + 4, T - 1)];
            if (ft == 0)      ekf_step<0>(damp, fG, a55, R, Qp, Qv, s0, s1, a, b, c, z, local);
            else if (ft == 1) ekf_step<1>(damp, fG, a55, R, Qp, Qv, s0, s1, a, b, c, z, local);
            else              ekf_step<2>(damp, fG, a55, R, Qp, Qv, s0, s1, a, b, c, z, local);
        }
    }

#pragma unroll
    for (int off = 32; off > 0; off >>= 1)
        local += __shfl_down(local, off, 64);
    if (lane == 0) atomicAdd(out, local * 0.5f / (float)N);
}

extern "C" void kernel_launch(void* const* d_in, const int* in_sizes, int n_in,
                              void* d_out, int out_size, void* d_ws, size_t ws_size,
                              hipStream_t stream) {
    const float* params     = (const float*)d_in[0];
    const float* cov_params = (const float*)d_in[1];
    const float* init_state = (const float*)d_in[2];
    const float* meas       = (const float*)d_in[3];
    float* out = (float*)d_out;

    const int N = in_sizes[2] / 6;
    const int T = in_sizes[3] / (N * 3);

    hipMemsetAsync(out, 0, sizeof(float), stream);

    dim3 grid((N + 63) / 64, 3);
    if (T == 64) {
        ekf_reg_kernel<64><<<grid, 64, 0, stream>>>(params, cov_params, init_state, meas, out, N);
    } else {
        ekf_gen_kernel<<<grid, 64, 0, stream>>>(params, cov_params, init_state, meas, out, N, T);
    }
}